// Round 5
// baseline (162.864 us; speedup 1.0000x reference)
//
#include <hip/hip_runtime.h>

// Problem shape (fixed by reference):
//   feat_s, feat_t : [64, 256, 32, 32] float32, integer values in [0,256)
//   out            : scalar float32
#define NBATCH    64
#define BINS      256
#define PER_BATCH (256 * 32 * 32)   // 262144 elements per batch
#define THREADS   256
#define CHUNKS    32                // blocks per batch-tensor
#define F4_PER_THREAD 8             // 32 elements/thread
#define F4_PER_CHUNK (F4_PER_THREAD * THREADS)  // 2048 float4 = 8192 elems/block

// ---------------------------------------------------------------------------
// Kernel 1: per-batch histograms, restructured for occupancy + MLP.
// LDS: 64 groups (bin>>2) x 64 columns x 4B = 16 KiB; each word packs 4 byte
// counters (bins 4g..4g+3). Column is the bank-bijective
//   col(lane) = (lane>>2) + 16*(lane&3)   (unique per lane 0..63)
// -> 2 lanes/bank (free, m136), ZERO intra-wave same-address collisions.
// A word is shared by the 4 threads (one per wave) with equal lane index:
// byte counter max = 4 thr x 32 elems = 128 <= 255, provably safe.
// 16 KiB LDS -> occupancy is waves-limited: 8 blocks/CU = 32 waves (100%).
// All 8 float4 loads issued up-front -> 8 outstanding loads/thread.
// grid = 128 batch-tensors * 32 chunks = 4096 blocks.
// ---------------------------------------------------------------------------
__global__ __launch_bounds__(THREADS, 8) void hist_kernel(
    const float* __restrict__ fs, const float* __restrict__ ft,
    int* __restrict__ phist) {
  __shared__ unsigned sh[64 * 64];  // 16 KiB
  const int tid = threadIdx.x;

  // zero LDS: 4096 words / 256 thr = 16 words = 4 x uint4 per thread
  uint4* shv = (uint4*)sh;
#pragma unroll
  for (int k = 0; k < 4; ++k) shv[k * THREADS + tid] = make_uint4(0, 0, 0, 0);
  __syncthreads();

  const int tb    = blockIdx.x >> 5;   // 0..127 : batch-tensor index
  const int chunk = blockIdx.x & 31;
  const float* src   = (tb < NBATCH) ? fs : ft;
  const int    batch = tb & (NBATCH - 1);
  const float4* p = (const float4*)(src + (size_t)batch * PER_BATCH)
                    + (size_t)chunk * F4_PER_CHUNK;

  const int lane = tid & 63;
  const unsigned colb = (unsigned)(((lane >> 2) + ((lane & 3) << 4)) << 2);

#define PROC1(x) {                                        \
    int b = ((int)(x)) & 255;                             \
    unsigned a = ((unsigned)(b >> 2) << 8) + colb;        \
    atomicAdd((unsigned*)((char*)sh + a),                 \
              1u << ((b & 3) << 3)); }
#define PROC4(v) { PROC1(v.x) PROC1(v.y) PROC1(v.z) PROC1(v.w) }

  // issue ALL loads up front (8 outstanding 16B loads per thread)
  float4 c[F4_PER_THREAD];
#pragma unroll
  for (int k = 0; k < F4_PER_THREAD; ++k) c[k] = p[k * THREADS + tid];
#pragma unroll
  for (int k = 0; k < F4_PER_THREAD; ++k) PROC4(c[k])
  __syncthreads();

  // Flush: thread t totals bin t. g = t>>2 (same for the quad), quarter
  // q = t&3 covers cols q*16..q*16+15; masked 16-bit field accumulation
  // (16*255 = 4080 per field, block bin total <= 8192 < 65536 after the
  // quad combine -> no carry). Quad shuffles merge the 4 quarters.
  const int g = tid >> 2;
  const unsigned qbase = (unsigned)g * 64u + (unsigned)(tid & 3) * 16u;
  unsigned acc0 = 0, acc1 = 0;
#pragma unroll
  for (int j = 0; j < 16; ++j) {
    unsigned w = sh[qbase + ((j + g) & 15)];
    acc0 += w & 0x00FF00FFu;          // bytes 0,2 -> bins 4g, 4g+2
    acc1 += (w >> 8) & 0x00FF00FFu;   // bytes 1,3 -> bins 4g+1, 4g+3
  }
  acc0 += __shfl_xor(acc0, 1);  acc0 += __shfl_xor(acc0, 2);
  acc1 += __shfl_xor(acc1, 1);  acc1 += __shfl_xor(acc1, 2);

  const int sub = tid & 3;
  unsigned cnt = (((sub & 1) ? acc1 : acc0) >> ((sub & 2) * 8)) & 0xFFFFu;
  phist[blockIdx.x * BINS + tid] = (int)cnt;   // private slab: plain store
}

// ---------------------------------------------------------------------------
// Kernel 2: per-batch KL partial, one block per batch (64 blocks x 256 thr).
// Sums the 32 chunk-histograms per tensor inline (coalesced), then fp64
// softmax/KL: result is a ~1e-3 sum of cancelling terms (threshold 1.9e-5).
// ---------------------------------------------------------------------------
__global__ __launch_bounds__(256) void kl_batch(
    const int* __restrict__ phist, double* __restrict__ partial) {
  __shared__ double reda[4], redb[4];
  const int n = blockIdx.x, tid = threadIdx.x;
  const int w = tid >> 6, lane = tid & 63;

  int hs = 0, ht = 0;
#pragma unroll 8
  for (int c = 0; c < CHUNKS; ++c) {
    hs += phist[(n * CHUNKS + c) * BINS + tid];
    ht += phist[((NBATCH + n) * CHUNKS + c) * BINS + tid];
  }

  // logits = log(hist + 1e-8) / T, T = 4
  double ls = log((double)hs + 1e-8) * 0.25;
  double lt = log((double)ht + 1e-8) * 0.25;

  double ms = ls, mt = lt;
  for (int off = 32; off; off >>= 1) {
    ms = fmax(ms, __shfl_xor(ms, off));
    mt = fmax(mt, __shfl_xor(mt, off));
  }
  if (lane == 0) { reda[w] = ms; redb[w] = mt; }
  __syncthreads();
  ms = fmax(fmax(reda[0], reda[1]), fmax(reda[2], reda[3]));
  mt = fmax(fmax(redb[0], redb[1]), fmax(redb[2], redb[3]));
  __syncthreads();

  double ss = exp(ls - ms), st = exp(lt - mt);
  for (int off = 32; off; off >>= 1) {
    ss += __shfl_xor(ss, off);
    st += __shfl_xor(st, off);
  }
  if (lane == 0) { reda[w] = ss; redb[w] = st; }
  __syncthreads();
  ss = reda[0] + reda[1] + reda[2] + reda[3];
  st = redb[0] + redb[1] + redb[2] + redb[3];
  const double lse_s = ms + log(ss);
  const double lse_t = mt + log(st);

  const double lpt = lt - lse_t;
  const double lps = ls - lse_s;
  double term = exp(lpt) * (lpt - lps);
  for (int off = 32; off; off >>= 1) term += __shfl_xor(term, off);
  __syncthreads();
  if (lane == 0) reda[w] = term;
  __syncthreads();
  if (tid == 0) partial[n] = reda[0] + reda[1] + reda[2] + reda[3];
}

// ---------------------------------------------------------------------------
// Kernel 3: sum 64 batch partials, scale by T^2/N = 16/64.
// ---------------------------------------------------------------------------
__global__ __launch_bounds__(64) void finalize(
    const double* __restrict__ partial, float* __restrict__ out) {
  double v = partial[threadIdx.x];
  for (int off = 32; off; off >>= 1) v += __shfl_xor(v, off);
  if (threadIdx.x == 0) out[0] = (float)(v * 0.25);
}

// ---------------------------------------------------------------------------
// DIAGNOSTIC (runs LAST, after d_out is final): pure-load mirror of hist's
// access pattern over feat_s (67 MB). Its dur_us isolates the read path:
// healthy ~12-15 us; if ~22+ us the read path itself is the hist ceiling.
// ---------------------------------------------------------------------------
__global__ __launch_bounds__(256) void probe_kernel(
    const float* __restrict__ src, float* __restrict__ pout) {
  const int tid = threadIdx.x;
  const float4* p = (const float4*)src + (size_t)blockIdx.x * F4_PER_CHUNK;
  float4 c[F4_PER_THREAD];
#pragma unroll
  for (int k = 0; k < F4_PER_THREAD; ++k) c[k] = p[k * THREADS + tid];
  float s = 0.f;
#pragma unroll
  for (int k = 0; k < F4_PER_THREAD; ++k) s += c[k].x + c[k].y + c[k].z + c[k].w;
  for (int off = 32; off; off >>= 1) s += __shfl_xor(s, off);
  if ((tid & 63) == 0) pout[(blockIdx.x << 2) + (tid >> 6)] = s;
}

// ---------------------------------------------------------------------------
extern "C" void kernel_launch(void* const* d_in, const int* in_sizes, int n_in,
                              void* d_out, int out_size, void* d_ws, size_t ws_size,
                              hipStream_t stream) {
  const float* fs = (const float*)d_in[0];
  const float* ft = (const float*)d_in[1];
  // ws: 4096 block-private 256-bin histograms (4 MiB) + 64 doubles + probe out.
  int*    phist   = (int*)d_ws;
  double* partial = (double*)((char*)d_ws + (size_t)128 * CHUNKS * BINS * sizeof(int));
  float*  pout    = (float*)((char*)d_ws + (size_t)128 * CHUNKS * BINS * sizeof(int) + 4096);

  hist_kernel<<<dim3(128 * CHUNKS), dim3(THREADS), 0, stream>>>(fs, ft, phist);
  kl_batch<<<dim3(NBATCH), dim3(256), 0, stream>>>(phist, partial);
  finalize<<<dim3(1), dim3(64), 0, stream>>>(partial, (float*)d_out);
  // diagnostic last: reads feat_s only, writes scratch (not d_out)
  probe_kernel<<<dim3(2048), dim3(THREADS), 0, stream>>>(fs, pout);
}

// Round 6
// 155.082 us; speedup vs baseline: 1.0502x; 1.0502x over previous
//
#include <hip/hip_runtime.h>

// Problem shape (fixed by reference):
//   feat_s, feat_t : [64, 256, 32, 32] float32, integer values in [0,256)
//   out            : scalar float32
#define NBATCH    64
#define BINS      256
#define PER_BATCH (256 * 32 * 32)   // 262144 elements per batch
#define THREADS   256
#define CHUNKS    16                // blocks per batch-tensor
#define F4_PER_THREAD 16            // 64 elements/thread (byte counters <= 64)
#define F4_PER_CHUNK (F4_PER_THREAD * THREADS)  // 4096 float4 per block

// ---------------------------------------------------------------------------
// Kernel 1: per-batch histograms with NO LDS ATOMICS.
// R1/R3/R5 invariant: 33.5M ds_add lane-atomics / 45us / 256CU = ~52 cyc per
// wave64 LDS atomic — the DS atomic RMW pipe is the ceiling (9x slower than
// ds_read's 5.8 cyc). Fix: thread-private counter words, plain read+add+write.
//   word = (bin>>2)*256 + tid   (64 groups x 256 cols = 64 KiB)
//   byte = bin&3; counter max = 64 elems/thread <= 255. No inter-thread races.
// Intra-thread hazard (two in-flight RMWs to the same word) is handled per
// float4-quad: all 4 reads issue first (compiler cannot hoist a may-aliasing
// store above a load; DS pipe is in-order per wave), increments are merged in
// registers for intra-quad group collisions, and aliased slots write the SAME
// final value so write order is irrelevant. Cross-quad hazard is covered by
// program-order stores-before-loads + in-order DS.
// grid = 128 batch-tensors * 16 chunks = 2048 blocks; 2 blocks/CU (64 KiB).
// ---------------------------------------------------------------------------
__global__ __launch_bounds__(THREADS) void hist_kernel(
    const float* __restrict__ fs, const float* __restrict__ ft,
    int* __restrict__ phist) {
  __shared__ unsigned sh[64 * 256];  // 64 KiB
  const int tid = threadIdx.x;

  // zero LDS: 16384 words / 256 thr = 64 words = 16 x uint4 per thread
  uint4* shv = (uint4*)sh;
#pragma unroll
  for (int k = 0; k < 16; ++k) shv[k * THREADS + tid] = make_uint4(0, 0, 0, 0);
  __syncthreads();

  const int tb    = blockIdx.x >> 4;   // 0..127 : batch-tensor index
  const int chunk = blockIdx.x & 15;
  const float* src   = (tb < NBATCH) ? fs : ft;
  const int    batch = tb & (NBATCH - 1);
  const float4* p = (const float4*)(src + (size_t)batch * PER_BATCH)
                    + (size_t)chunk * F4_PER_CHUNK;

  // Process one float4 (4 elements) as a merged RMW quad.
#define PROCQ(v) {                                                          \
    unsigned b0 = (unsigned)(v).x & 255u, b1 = (unsigned)(v).y & 255u,      \
             b2 = (unsigned)(v).z & 255u, b3 = (unsigned)(v).w & 255u;      \
    unsigned g0 = b0 >> 2, g1 = b1 >> 2, g2 = b2 >> 2, g3 = b3 >> 2;        \
    unsigned i0 = 1u << ((b0 & 3u) << 3), i1 = 1u << ((b1 & 3u) << 3),      \
             i2 = 1u << ((b2 & 3u) << 3), i3 = 1u << ((b3 & 3u) << 3);      \
    bool e10 = g1 == g0, e20 = g2 == g0, e21 = g2 == g1;                    \
    bool e30 = g3 == g0, e31 = g3 == g1, e32 = g3 == g2;                    \
    unsigned m0 = i0 + (e10 ? i1 : 0u) + (e20 ? i2 : 0u) + (e30 ? i3 : 0u); \
    unsigned m1 = i1 + ((e21 && !e20) ? i2 : 0u)                            \
                     + ((e31 && !e30) ? i3 : 0u);                           \
    unsigned m2 = i2 + ((e32 && !e31 && !e30) ? i3 : 0u);                   \
    unsigned x0 = (g0 << 8) + (unsigned)tid, x1 = (g1 << 8) + (unsigned)tid,\
             x2 = (g2 << 8) + (unsigned)tid, x3 = (g3 << 8) + (unsigned)tid;\
    unsigned u0 = sh[x0], u1 = sh[x1], u2 = sh[x2], u3 = sh[x3];            \
    unsigned f1 = e10 ? m0 : m1;                                            \
    unsigned f2 = e20 ? m0 : (e21 ? f1 : m2);                               \
    unsigned f3 = e30 ? m0 : (e31 ? f1 : (e32 ? f2 : i3));                  \
    sh[x0] = u0 + m0; sh[x1] = u1 + f1;                                     \
    sh[x2] = u2 + f2; sh[x3] = u3 + f3; }

  // 4-deep float4 prefetch pipeline over 16 float4 per thread
  float4 c[4];
#pragma unroll
  for (int k = 0; k < 4; ++k) c[k] = p[k * THREADS + tid];
#pragma unroll
  for (int it = 0; it < 3; ++it) {
#pragma unroll
    for (int k = 0; k < 4; ++k) {
      float4 n = p[((it + 1) * 4 + k) * THREADS + tid];
      PROCQ(c[k])
      c[k] = n;
    }
  }
#pragma unroll
  for (int k = 0; k < 4; ++k) PROCQ(c[k])
  __syncthreads();

  // Flush: thread t totals bin t. g = t>>2, quarter q = t&3 owns cols
  // q*64..q*64+63; masked 16-bit field accumulation (64 cols x <=64 = 4096
  // per field; quad-combined <= 16384 < 65536 -> no carry). Rotation (j+t)&63
  // keeps banks at 2 lanes/bank (free).
  const int g = tid >> 2;
  const unsigned qbase = (unsigned)g * 256u + (unsigned)(tid & 3) * 64u;
  unsigned acc0 = 0, acc1 = 0;
#pragma unroll 4
  for (int j = 0; j < 64; ++j) {
    unsigned w = sh[qbase + ((j + tid) & 63)];
    acc0 += w & 0x00FF00FFu;          // bytes 0,2 -> bins 4g, 4g+2
    acc1 += (w >> 8) & 0x00FF00FFu;   // bytes 1,3 -> bins 4g+1, 4g+3
  }
  acc0 += __shfl_xor(acc0, 1);  acc0 += __shfl_xor(acc0, 2);
  acc1 += __shfl_xor(acc1, 1);  acc1 += __shfl_xor(acc1, 2);

  const int sub = tid & 3;
  unsigned cnt = (((sub & 1) ? acc1 : acc0) >> ((sub & 2) * 8)) & 0xFFFFu;
  phist[blockIdx.x * BINS + tid] = (int)cnt;   // private slab: plain store
}

// ---------------------------------------------------------------------------
// Kernel 2: per-batch KL partial, one block per batch (64 blocks x 256 thr).
// Sums the 16 chunk-histograms per tensor inline (coalesced), then fp64
// softmax/KL: result is a ~1e-3 sum of cancelling terms (threshold 1.9e-5).
// ---------------------------------------------------------------------------
__global__ __launch_bounds__(256) void kl_batch(
    const int* __restrict__ phist, double* __restrict__ partial) {
  __shared__ double reda[4], redb[4];
  const int n = blockIdx.x, tid = threadIdx.x;
  const int w = tid >> 6, lane = tid & 63;

  int hs = 0, ht = 0;
#pragma unroll
  for (int c = 0; c < CHUNKS; ++c) {
    hs += phist[(n * CHUNKS + c) * BINS + tid];
    ht += phist[((NBATCH + n) * CHUNKS + c) * BINS + tid];
  }

  // logits = log(hist + 1e-8) / T, T = 4
  double ls = log((double)hs + 1e-8) * 0.25;
  double lt = log((double)ht + 1e-8) * 0.25;

  double ms = ls, mt = lt;
  for (int off = 32; off; off >>= 1) {
    ms = fmax(ms, __shfl_xor(ms, off));
    mt = fmax(mt, __shfl_xor(mt, off));
  }
  if (lane == 0) { reda[w] = ms; redb[w] = mt; }
  __syncthreads();
  ms = fmax(fmax(reda[0], reda[1]), fmax(reda[2], reda[3]));
  mt = fmax(fmax(redb[0], redb[1]), fmax(redb[2], redb[3]));
  __syncthreads();

  double ss = exp(ls - ms), st = exp(lt - mt);
  for (int off = 32; off; off >>= 1) {
    ss += __shfl_xor(ss, off);
    st += __shfl_xor(st, off);
  }
  if (lane == 0) { reda[w] = ss; redb[w] = st; }
  __syncthreads();
  ss = reda[0] + reda[1] + reda[2] + reda[3];
  st = redb[0] + redb[1] + redb[2] + redb[3];
  const double lse_s = ms + log(ss);
  const double lse_t = mt + log(st);

  const double lpt = lt - lse_t;
  const double lps = ls - lse_s;
  double term = exp(lpt) * (lpt - lps);
  for (int off = 32; off; off >>= 1) term += __shfl_xor(term, off);
  __syncthreads();
  if (lane == 0) reda[w] = term;
  __syncthreads();
  if (tid == 0) partial[n] = reda[0] + reda[1] + reda[2] + reda[3];
}

// ---------------------------------------------------------------------------
// Kernel 3: sum 64 batch partials, scale by T^2/N = 16/64.
// ---------------------------------------------------------------------------
__global__ __launch_bounds__(64) void finalize(
    const double* __restrict__ partial, float* __restrict__ out) {
  double v = partial[threadIdx.x];
  for (int off = 32; off; off >>= 1) v += __shfl_xor(v, off);
  if (threadIdx.x == 0) out[0] = (float)(v * 0.25);
}

// ---------------------------------------------------------------------------
extern "C" void kernel_launch(void* const* d_in, const int* in_sizes, int n_in,
                              void* d_out, int out_size, void* d_ws, size_t ws_size,
                              hipStream_t stream) {
  const float* fs = (const float*)d_in[0];
  const float* ft = (const float*)d_in[1];
  // ws: 2048 block-private 256-bin histograms (2 MiB) + 64 doubles.
  int*    phist   = (int*)d_ws;
  double* partial = (double*)((char*)d_ws + (size_t)128 * CHUNKS * BINS * sizeof(int));

  hist_kernel<<<dim3(128 * CHUNKS), dim3(THREADS), 0, stream>>>(fs, ft, phist);
  kl_batch<<<dim3(NBATCH), dim3(256), 0, stream>>>(phist, partial);
  finalize<<<dim3(1), dim3(64), 0, stream>>>(partial, (float*)d_out);
}